// Round 1
// baseline (433.429 us; speedup 1.0000x reference)
//
#include <hip/hip_runtime.h>
#include <cmath>

#define BATCH_DIV 32   // b-values per block in main kernel

// ---------------- Kernel 1: x_red[b,r] = sum_i x[b,i] * mask[r,i] ----------------
// mask is identity in practice -> result exact (adds of 0.0 are exact).
__global__ __launch_bounds__(256) void xred_kernel(const float* __restrict__ x,
                                                   const float* __restrict__ mask,
                                                   float* __restrict__ xred) {
    __shared__ float xs[8][128];
    const int tid = threadIdx.x;
    const int bbase = blockIdx.x * 8;
    // stage 8 rows of x into LDS (coalesced)
    for (int k = tid; k < 8 * 128; k += 256) {
        xs[k >> 7][k & 127] = x[(size_t)(bbase + (k >> 7)) * 128 + (k & 127)];
    }
    __syncthreads();
    const int r = tid & 127;
    const int h = tid >> 7;          // 0/1 -> rows h*4 .. h*4+3
    const float* mrow = mask + (size_t)r * 128;
    float acc0 = 0.f, acc1 = 0.f, acc2 = 0.f, acc3 = 0.f;
    for (int i = 0; i < 128; ++i) {
        float m = mrow[i];
        acc0 += m * xs[h * 4 + 0][i];
        acc1 += m * xs[h * 4 + 1][i];
        acc2 += m * xs[h * 4 + 2][i];
        acc3 += m * xs[h * 4 + 3][i];
    }
    xred[(size_t)(bbase + h * 4 + 0) * 128 + r] = acc0;
    xred[(size_t)(bbase + h * 4 + 1) * 128 + r] = acc1;
    xred[(size_t)(bbase + h * 4 + 2) * 128 + r] = acc2;
    xred[(size_t)(bbase + h * 4 + 3) * 128 + r] = acc3;
}

// ---------------- function select (matches jnp.select branch list) ----------------
__device__ __forceinline__ float apply_fun(int id, float z) {
    switch (id) {
        case 0: return z;
        case 1: return z * z;
        case 2: return z * z * z;
        case 3: return sinf(z);
        case 4: return tanhf(z);
        case 5: return 1.0f / (1.0f + expf(-z));
        case 6: return expf(-z * z);
        case 7: return fabsf(z);
        case 8: return atanf(z);
        default: return expf(z);     // id 9
    }
}

// ---------------- Kernel 2: z, postacts, y ----------------
// grid: (out_f=128, batch/32). block: 256 = 4 waves.
// lane = i (thread covers i and i+64); wave w handles b = base + w + 4*iter.
__global__ __launch_bounds__(256) void kan_main(const float* __restrict__ xred,
                                                const float4* __restrict__ affine,
                                                const int* __restrict__ fun_ids,
                                                float* __restrict__ y,
                                                float* __restrict__ postacts) {
    const int tid  = threadIdx.x;
    const int lane = tid & 63;
    const int w    = tid >> 6;       // wave id 0..3
    const int o    = blockIdx.x;     // out feature
    const int i0   = lane;
    const int i1   = lane + 64;

    // per-(o,i) constants: a,b,c,d packed as float4, plus fun id (batch-invariant)
    const float4 A0 = affine[o * 128 + i0];
    const float4 A1 = affine[o * 128 + i1];
    const int   f0  = fun_ids[o * 128 + i0];
    const int   f1  = fun_ids[o * 128 + i1];

    const int bbase = blockIdx.y * BATCH_DIV + w;

    for (int it = 0; it < BATCH_DIV / 4; ++it) {
        const int b = bbase + 4 * it;
        const float xr0 = xred[(size_t)b * 128 + i0];
        const float xr1 = xred[(size_t)b * 128 + i1];

        const float z0 = A0.x * xr0 + A0.y;
        const float z1 = A1.x * xr1 + A1.y;

        const float g0 = apply_fun(f0, z0);
        const float g1 = apply_fun(f1, z1);

        const float p0 = A0.z * g0 + A0.w;
        const float p1 = A1.z * g1 + A1.w;

        float* row = postacts + ((size_t)b * 128 + o) * 128;
        row[i0] = p0;
        row[i1] = p1;

        // y[b,o] = sum over all 128 i  (wave-level shuffle reduce)
        float s = p0 + p1;
        #pragma unroll
        for (int off = 32; off > 0; off >>= 1) s += __shfl_down(s, off, 64);
        if (lane == 0) y[(size_t)b * 128 + o] = s;
    }
}

extern "C" void kernel_launch(void* const* d_in, const int* in_sizes, int n_in,
                              void* d_out, int out_size, void* d_ws, size_t ws_size,
                              hipStream_t stream) {
    const float* x       = (const float*)d_in[0];   // (batch, 128)
    const float* affine  = (const float*)d_in[1];   // (128, 128, 4)
    const float* mask    = (const float*)d_in[2];   // (128, 128)
    const int*   fun_ids = (const int*)d_in[3];     // (128, 128)

    const int batch = in_sizes[0] / 128;            // 4096

    float* xred     = (float*)d_ws;                 // batch*128 floats (2 MB)
    float* y        = (float*)d_out;                // batch*128
    float* postacts = y + (size_t)batch * 128;      // batch*128*128

    xred_kernel<<<dim3(batch / 8), dim3(256), 0, stream>>>(x, mask, xred);

    kan_main<<<dim3(128, batch / BATCH_DIV), dim3(256), 0, stream>>>(
        xred, (const float4*)affine, fun_ids, y, postacts);
}

// Round 2
// 303.731 us; speedup vs baseline: 1.4270x; 1.4270x over previous
//
#include <hip/hip_runtime.h>
#include <cmath>

#define BATCH_DIV 64   // b-values per block in main kernel
#define XR_BB     16   // b-rows per block in xred kernel

// ---------------- Kernel 1: x_red[b,r] = sum_i x[b,i] * mask[r,i] ----------------
// Full mask staged in LDS (padded rows, conflict-free), x staged transposed so the
// inner loop is broadcast ds_read_b128.
__global__ __launch_bounds__(256) void xred_kernel(const float* __restrict__ x,
                                                   const float* __restrict__ mask,
                                                   float* __restrict__ xred) {
    __shared__ float ms[128][129];   // +1 pad: compute-read bank = (r+i)&31 -> 2-way = free
    __shared__ float xs[128][20];    // transposed [i][b], pad 20 keeps 16B align for float4
    const int tid   = threadIdx.x;
    const int bbase = blockIdx.x * XR_BB;

    // stage mask: 16384 floats via float4 global loads (coalesced)
    const float4* m4 = (const float4*)mask;
    for (int k = tid; k < 4096; k += 256) {
        float4 v = m4[k];
        int row = k >> 5;            // 32 float4 per 128-wide row
        int col = (k & 31) * 4;
        ms[row][col]     = v.x;
        ms[row][col + 1] = v.y;
        ms[row][col + 2] = v.z;
        ms[row][col + 3] = v.w;
    }
    // stage x transposed
    for (int k = tid; k < XR_BB * 128; k += 256) {
        int b = k >> 7, i = k & 127;
        xs[i][b] = x[(size_t)(bbase + b) * 128 + i];
    }
    __syncthreads();

    const int r = tid & 127;
    const int g = tid >> 7;          // 0/1 -> b offset 8g
    float acc[8] = {0.f, 0.f, 0.f, 0.f, 0.f, 0.f, 0.f, 0.f};
    for (int i = 0; i < 128; ++i) {
        const float  m  = ms[r][i];                          // 2-way alias, free
        const float4 xa = *(const float4*)&xs[i][8 * g];     // broadcast b128
        const float4 xb = *(const float4*)&xs[i][8 * g + 4]; // broadcast b128
        acc[0] += m * xa.x; acc[1] += m * xa.y; acc[2] += m * xa.z; acc[3] += m * xa.w;
        acc[4] += m * xb.x; acc[5] += m * xb.y; acc[6] += m * xb.z; acc[7] += m * xb.w;
    }
    #pragma unroll
    for (int j = 0; j < 8; ++j)
        xred[(size_t)(bbase + 8 * g + j) * 128 + r] = acc[j];
}

// ---------------- Kernel 2: z, postacts, y ----------------
// grid: (out_f=128, batch/BATCH_DIV). block 256 = 4 waves; wave w owns b = base+w+4*it.
// lane owns i-pair (2*lane, 2*lane+1) -> float2 stores. fun_ids are batch-invariant:
// all id-dependent masks/coefs hoisted out of the b-loop.
__global__ __launch_bounds__(256) void kan_main(const float2* __restrict__ xred,
                                                const float4* __restrict__ affine,
                                                const int* __restrict__ fun_ids,
                                                float* __restrict__ y,
                                                float2* __restrict__ postacts) {
    const int tid  = threadIdx.x;
    const int lane = tid & 63;
    const int w    = tid >> 6;
    const int o    = blockIdx.x;
    const int i0   = 2 * lane;
    const int i1   = 2 * lane + 1;

    const float4 A0 = affine[o * 128 + i0];
    const float4 A1 = affine[o * 128 + i1];
    const int    f0 = fun_ids[o * 128 + i0];
    const int    f1 = fun_ids[o * 128 + i1];

    // hoisted per-id predicates (wave masks) ----------------------------------
    const bool m1_0 = (f0 == 1), m2_0 = (f0 == 2), m7_0 = (f0 == 7), m3_0 = (f0 == 3), m8_0 = (f0 == 8);
    const bool m1_1 = (f1 == 1), m2_1 = (f1 == 2), m7_1 = (f1 == 7), m3_1 = (f1 == 3), m8_1 = (f1 == 8);
    const bool me_0 = (f0 >= 4 && f0 <= 6) || (f0 == 9);
    const bool me_1 = (f1 >= 4 && f1 <= 6) || (f1 == 9);

    // hoisted exp-group coefficients: arg = k1*z + k2*z^2 ; r = (An + Bn*e)/(1 + Dd*e)
    float k1_0 = 0.f, k2_0 = 0.f, An_0 = 0.f, Bn_0 = 1.f, Dd_0 = 0.f;
    if      (f0 == 4) { k1_0 = -2.f; An_0 = 1.f; Bn_0 = -1.f; Dd_0 = 1.f; }   // tanh
    else if (f0 == 5) { k1_0 = -1.f; An_0 = 1.f; Bn_0 =  0.f; Dd_0 = 1.f; }   // sigmoid
    else if (f0 == 6) { k2_0 = -1.f; }                                        // exp(-z^2)
    else if (f0 == 9) { k1_0 =  1.f; }                                        // exp(z)
    float k1_1 = 0.f, k2_1 = 0.f, An_1 = 0.f, Bn_1 = 1.f, Dd_1 = 0.f;
    if      (f1 == 4) { k1_1 = -2.f; An_1 = 1.f; Bn_1 = -1.f; Dd_1 = 1.f; }
    else if (f1 == 5) { k1_1 = -1.f; An_1 = 1.f; Bn_1 =  0.f; Dd_1 = 1.f; }
    else if (f1 == 6) { k2_1 = -1.f; }
    else if (f1 == 9) { k1_1 =  1.f; }

    const int bbase = blockIdx.y * BATCH_DIV + w;

    for (int it = 0; it < BATCH_DIV / 4; ++it) {
        const int b = bbase + 4 * it;
        const float2 xr = xred[(size_t)b * 64 + lane];

        // ---- element 0 ----
        float p0;
        {
            const float z  = fmaf(A0.x, xr.x, A0.y);
            const float zz = z * z;
            float p = m1_0 ? zz : z;
            p = m2_0 ? zz * z : p;
            p = m7_0 ? fabsf(z) : p;
            const float s = __sinf(z);
            p = m3_0 ? s : p;
            float arg = fminf(fmaf(k2_0, zz, k1_0 * z), 80.f);
            const float e   = __expf(arg);
            const float num = fmaf(Bn_0, e, An_0);
            const float den = fmaf(Dd_0, e, 1.0f);
            const float r   = num * __builtin_amdgcn_rcpf(den);
            p = me_0 ? r : p;
            const float az  = fabsf(z);
            const bool  big = az > 1.0f;
            const float t   = big ? __builtin_amdgcn_rcpf(az) : az;
            const float t2  = t * t;
            float q = fmaf(t2, -0.01172120f, 0.05265332f);
            q = fmaf(t2, q, -0.11643287f);
            q = fmaf(t2, q,  0.19354346f);
            q = fmaf(t2, q, -0.33262347f);
            q = fmaf(t2, q,  0.99997726f);
            q = t * q;
            q = big ? 1.57079632679f - q : q;
            const float at = copysignf(q, z);
            p = m8_0 ? at : p;
            p0 = fmaf(A0.z, p, A0.w);
        }
        // ---- element 1 ----
        float p1;
        {
            const float z  = fmaf(A1.x, xr.y, A1.y);
            const float zz = z * z;
            float p = m1_1 ? zz : z;
            p = m2_1 ? zz * z : p;
            p = m7_1 ? fabsf(z) : p;
            const float s = __sinf(z);
            p = m3_1 ? s : p;
            float arg = fminf(fmaf(k2_1, zz, k1_1 * z), 80.f);
            const float e   = __expf(arg);
            const float num = fmaf(Bn_1, e, An_1);
            const float den = fmaf(Dd_1, e, 1.0f);
            const float r   = num * __builtin_amdgcn_rcpf(den);
            p = me_1 ? r : p;
            const float az  = fabsf(z);
            const bool  big = az > 1.0f;
            const float t   = big ? __builtin_amdgcn_rcpf(az) : az;
            const float t2  = t * t;
            float q = fmaf(t2, -0.01172120f, 0.05265332f);
            q = fmaf(t2, q, -0.11643287f);
            q = fmaf(t2, q,  0.19354346f);
            q = fmaf(t2, q, -0.33262347f);
            q = fmaf(t2, q,  0.99997726f);
            q = t * q;
            q = big ? 1.57079632679f - q : q;
            const float at = copysignf(q, z);
            p = m8_1 ? at : p;
            p1 = fmaf(A1.z, p, A1.w);
        }

        postacts[((size_t)b * 128 + o) * 64 + lane] = make_float2(p0, p1);

        float s = p0 + p1;
        #pragma unroll
        for (int off = 32; off > 0; off >>= 1) s += __shfl_down(s, off, 64);
        if (lane == 0) y[(size_t)b * 128 + o] = s;
    }
}

extern "C" void kernel_launch(void* const* d_in, const int* in_sizes, int n_in,
                              void* d_out, int out_size, void* d_ws, size_t ws_size,
                              hipStream_t stream) {
    const float* x       = (const float*)d_in[0];   // (batch, 128)
    const float* affine  = (const float*)d_in[1];   // (128, 128, 4)
    const float* mask    = (const float*)d_in[2];   // (128, 128)
    const int*   fun_ids = (const int*)d_in[3];     // (128, 128)

    const int batch = in_sizes[0] / 128;            // 4096

    float* xred     = (float*)d_ws;                 // batch*128 floats (2 MB)
    float* y        = (float*)d_out;                // batch*128
    float* postacts = y + (size_t)batch * 128;      // batch*128*128

    xred_kernel<<<dim3(batch / XR_BB), dim3(256), 0, stream>>>(x, mask, xred);

    kan_main<<<dim3(128, batch / BATCH_DIV), dim3(256), 0, stream>>>(
        (const float2*)xred, (const float4*)affine, fun_ids, y, (float2*)postacts);
}